// Round 4
// baseline (798.038 us; speedup 1.0000x reference)
//
#include <hip/hip_runtime.h>

// f32 I/O. K=8 expert AEs, B=8192, D=1024, H=256.
//   h = relu(x @ W1[k] + b1[k]); recon = h @ W2[k] + b2[k]
//   err[k,b] = mean((recon-x)^2); out[b] = recon[argmin_k err, b]
// Precision (validated R2): pass1 err via split-bf16 hi/lo 3-product GEMMs;
// pass2 winner recon plain bf16-hi.
// R4: barrier-free pass1 phases. x pre-split to xh/xl (global A-frags, no LDS
// staging, no per-step barriers); BM=64 (2x W amortization); nontemporal x
// loads (keep W L2-resident); h tile in 64KB static LDS, XOR-swizzled
// (col ^ ((row&7)<<3)) for <=2-way conflicts. One barrier between phases.

#define KE 8
#define NB 8192
#define ND 1024
#define NH 256

typedef float f32x4 __attribute__((ext_vector_type(4)));
typedef short s16x8 __attribute__((ext_vector_type(8)));
typedef unsigned short u16x8 __attribute__((ext_vector_type(8)));
typedef unsigned short u16x4 __attribute__((ext_vector_type(4)));

__device__ __forceinline__ float bf2f(unsigned short h) {
  union { unsigned int u; float f; } v; v.u = ((unsigned int)h) << 16; return v.f;
}
__device__ __forceinline__ unsigned short f2bf(float f) {
  union { unsigned int u; float f; } v; v.f = f;
  unsigned int u = v.u;
  u += 0x7fffu + ((u >> 16) & 1u);   // RTNE
  return (unsigned short)(u >> 16);
}
__device__ __forceinline__ void split2(float x, unsigned short& hi, unsigned short& lo) {
  hi = f2bf(x);
  lo = f2bf(x - bf2f(hi));
}
__device__ __forceinline__ s16x8 ntld8(const unsigned short* p) {
  return __builtin_nontemporal_load((const s16x8*)p);
}
// two 8B LDS reads (8B-aligned)
__device__ __forceinline__ s16x8 rd8(const unsigned short* p) {
  u16x4 a = *(const u16x4*)p;
  u16x4 b = *(const u16x4*)(p + 4);
  s16x8 r;
  r[0] = a[0]; r[1] = a[1]; r[2] = a[2]; r[3] = a[3];
  r[4] = b[0]; r[5] = b[1]; r[6] = b[2]; r[7] = b[3];
  return r;
}

// ---- x[b][d] f32 -> xh/xl bf16
__global__ __launch_bounds__(256) void split_x(const float* __restrict__ in,
                                               unsigned short* __restrict__ oh,
                                               unsigned short* __restrict__ ol) {
  size_t g = ((size_t)blockIdx.x * 256 + threadIdx.x) * 4;
  float4 v = *(const float4*)&in[g];
  unsigned short th[4], tl[4];
  split2(v.x, th[0], tl[0]); split2(v.y, th[1], tl[1]);
  split2(v.z, th[2], tl[2]); split2(v.w, th[3], tl[3]);
  *(u16x4*)&oh[g] = *(u16x4*)th;
  *(u16x4*)&ol[g] = *(u16x4*)tl;
}

// ---- W1[k][d][h] f32 -> w1t_hi/lo[k][h][d] bf16
__global__ __launch_bounds__(256) void split_w1(const float* __restrict__ in,
                                                unsigned short* __restrict__ oh,
                                                unsigned short* __restrict__ ol) {
  int g = blockIdx.x * 256 + threadIdx.x;   // K*NH*(ND/8) = 262144
  int k = g >> 15;
  int r = g & 32767;
  int j = r & (NH - 1);
  int d8 = (r >> 8) * 8;
  unsigned short th[8], tl[8];
#pragma unroll
  for (int q = 0; q < 8; ++q) {
    float v = in[((size_t)k * ND + d8 + q) * NH + j];
    split2(v, th[q], tl[q]);
  }
  size_t o = ((size_t)k * NH + j) * ND + d8;
  *(u16x8*)&oh[o] = *(u16x8*)th;
  *(u16x8*)&ol[o] = *(u16x8*)tl;
}

// ---- W2[k][h][d] f32 -> w2t_hi/lo[k][d][h] bf16
__global__ __launch_bounds__(256) void split_w2(const float* __restrict__ in,
                                                unsigned short* __restrict__ oh,
                                                unsigned short* __restrict__ ol) {
  int g = blockIdx.x * 256 + threadIdx.x;
  int k = g >> 15;
  int r = g & 32767;
  int d = r & (ND - 1);
  int h8 = (r >> 10) * 8;
  unsigned short th[8], tl[8];
#pragma unroll
  for (int q = 0; q < 8; ++q) {
    float v = in[((size_t)k * NH + h8 + q) * ND + d];
    split2(v, th[q], tl[q]);
  }
  size_t o = ((size_t)k * ND + d) * NH + h8;
  *(u16x8*)&oh[o] = *(u16x8*)th;
  *(u16x8*)&ol[o] = *(u16x8*)tl;
}

// ---- pass 1: split-precision err[K][B]. BM=64, grid 1024, expert = bx & 7.
__global__ __launch_bounds__(256, 2) void ae_pass1(
    const unsigned short* __restrict__ xh, const unsigned short* __restrict__ xl,
    const float* __restrict__ x,
    const unsigned short* __restrict__ w1h, const unsigned short* __restrict__ w1l,
    const float* __restrict__ b1,
    const unsigned short* __restrict__ w2h, const unsigned short* __restrict__ w2l,
    const float* __restrict__ b2, float* __restrict__ err) {
  __shared__ union {
    struct { unsigned short h[64][256]; unsigned short l[64][256]; } hs;  // 65536 B
    float errp[4][64];
  } s;

  const int tid = threadIdx.x;
  const int wv = tid >> 6;
  const int lane = tid & 63;
  const int lo = lane & 15;
  const int quad = lane >> 4;
  const int k = blockIdx.x & 7;
  const int r0 = (blockIdx.x >> 3) * 64;

  // ---------- phase A: h = relu(x@W1+b1), M=64, N=256 (wave: 64 cols), Kd=1024
  // Barrier-free: A-frags of x from global (xh/xl, nt), B-frags of W1 from global.
  f32x4 acc1[4][4];
#pragma unroll
  for (int mt = 0; mt < 4; ++mt)
#pragma unroll
    for (int nt = 0; nt < 4; ++nt) acc1[mt][nt] = (f32x4){0.f, 0.f, 0.f, 0.f};

#pragma unroll 2
  for (int it = 0; it < ND / 32; ++it) {
    const int kk = it * 32;
    s16x8 ah[4], al[4], bh[4], bl[4];
#pragma unroll
    for (int mt = 0; mt < 4; ++mt) {
      size_t o = ((size_t)(r0 + mt * 16 + lo)) * ND + kk + quad * 8;
      ah[mt] = ntld8(&xh[o]);
      al[mt] = ntld8(&xl[o]);
    }
#pragma unroll
    for (int nt = 0; nt < 4; ++nt) {
      size_t wo = ((size_t)k * NH + wv * 64 + nt * 16 + lo) * ND + kk + quad * 8;
      bh[nt] = *(const s16x8*)&w1h[wo];
      bl[nt] = *(const s16x8*)&w1l[wo];
    }
#pragma unroll
    for (int nt = 0; nt < 4; ++nt)
#pragma unroll
      for (int mt = 0; mt < 4; ++mt) {
        acc1[mt][nt] = __builtin_amdgcn_mfma_f32_16x16x32_bf16(ah[mt], bh[nt], acc1[mt][nt], 0, 0, 0);
        acc1[mt][nt] = __builtin_amdgcn_mfma_f32_16x16x32_bf16(ah[mt], bl[nt], acc1[mt][nt], 0, 0, 0);
        acc1[mt][nt] = __builtin_amdgcn_mfma_f32_16x16x32_bf16(al[mt], bh[nt], acc1[mt][nt], 0, 0, 0);
      }
  }

  // epilogue A: +b1, relu, split h -> LDS swizzled (C/D: col=lo, row=quad*4+i)
#pragma unroll
  for (int nt = 0; nt < 4; ++nt) {
    float b1v = b1[(size_t)k * NH + wv * 64 + nt * 16 + lo];
#pragma unroll
    for (int mt = 0; mt < 4; ++mt)
#pragma unroll
      for (int i = 0; i < 4; ++i) {
        float v = acc1[mt][nt][i] + b1v;
        v = v > 0.f ? v : 0.f;
        unsigned short vh, vl;
        split2(v, vh, vl);
        int row = mt * 16 + quad * 4 + i, col = wv * 64 + nt * 16 + lo;
        int sc = col ^ ((row & 7) << 3);
        s.hs.h[row][sc] = vh;
        s.hs.l[row][sc] = vl;
      }
  }
  __syncthreads();   // the ONE inter-phase barrier

  // ---------- phase B: recon = h@W2+b2, 128-wide chunks; wave: 32 cols (2 nt)
  float eacc[4][4];
#pragma unroll
  for (int mt = 0; mt < 4; ++mt)
#pragma unroll
    for (int i = 0; i < 4; ++i) eacc[mt][i] = 0.f;

  for (int c = 0; c < ND / 128; ++c) {
    const int d2w = c * 128 + wv * 32;
    f32x4 acc2[4][2];
#pragma unroll
    for (int mt = 0; mt < 4; ++mt)
#pragma unroll
      for (int nt = 0; nt < 2; ++nt) acc2[mt][nt] = (f32x4){0.f, 0.f, 0.f, 0.f};

#pragma unroll
    for (int kc = 0; kc < NH / 32; ++kc) {
      s16x8 hah[4], hal[4];
#pragma unroll
      for (int mt = 0; mt < 4; ++mt) {
        int row = mt * 16 + lo;
        int off = row * 256 + ((kc * 32 + quad * 8) ^ ((row & 7) << 3));
        hah[mt] = rd8(&s.hs.h[0][0] + off);
        hal[mt] = rd8(&s.hs.l[0][0] + off);
      }
#pragma unroll
      for (int nt = 0; nt < 2; ++nt) {
        size_t wo = ((size_t)k * ND + d2w + nt * 16 + lo) * NH + kc * 32 + quad * 8;
        s16x8 bh = *(const s16x8*)&w2h[wo];
        s16x8 bl = *(const s16x8*)&w2l[wo];
#pragma unroll
        for (int mt = 0; mt < 4; ++mt) {
          acc2[mt][nt] = __builtin_amdgcn_mfma_f32_16x16x32_bf16(hah[mt], bh, acc2[mt][nt], 0, 0, 0);
          acc2[mt][nt] = __builtin_amdgcn_mfma_f32_16x16x32_bf16(hah[mt], bl, acc2[mt][nt], 0, 0, 0);
          acc2[mt][nt] = __builtin_amdgcn_mfma_f32_16x16x32_bf16(hal[mt], bh, acc2[mt][nt], 0, 0, 0);
        }
      }
    }
#pragma unroll
    for (int nt = 0; nt < 2; ++nt) {
      float b2v = b2[(size_t)k * ND + d2w + nt * 16 + lo];
#pragma unroll
      for (int mt = 0; mt < 4; ++mt)
#pragma unroll
        for (int i = 0; i < 4; ++i) {
          int row = mt * 16 + quad * 4 + i;
          float rec = acc2[mt][nt][i] + b2v;
          float xv = __builtin_nontemporal_load(&x[(size_t)(r0 + row) * ND + d2w + nt * 16 + lo]);
          float dd = rec - xv;
          eacc[mt][i] += dd * dd;
        }
    }
  }

  __syncthreads();   // all hs reads done before errp aliases the union
#pragma unroll
  for (int mt = 0; mt < 4; ++mt)
#pragma unroll
    for (int i = 0; i < 4; ++i) {
      float v = eacc[mt][i];
      v += __shfl_xor(v, 1, 16);
      v += __shfl_xor(v, 2, 16);
      v += __shfl_xor(v, 4, 16);
      v += __shfl_xor(v, 8, 16);
      if (lo == 0) s.errp[wv][mt * 16 + quad * 4 + i] = v;
    }
  __syncthreads();
  if (tid < 64)
    err[(size_t)k * NB + r0 + tid] =
        (s.errp[0][tid] + s.errp[1][tid] + s.errp[2][tid] + s.errp[3][tid]) * (1.0f / (float)ND);
}

// ---- argmin + bucket rows per expert
__global__ __launch_bounds__(256) void ae_argmin(const float* __restrict__ err,
                                                 unsigned int* __restrict__ cnt,
                                                 int* __restrict__ bucket) {
  __shared__ unsigned int lc[KE];
  __shared__ unsigned int base[KE];
  int tid = threadIdx.x;
  if (tid < KE) lc[tid] = 0;
  __syncthreads();
  int b = blockIdx.x * 256 + tid;
  float best = err[b];
  int kmin = 0;
#pragma unroll
  for (int j = 1; j < KE; ++j) {
    float e = err[(size_t)j * NB + b];
    if (e < best) { best = e; kmin = j; }   // strict < == first-min (jnp.argmin)
  }
  unsigned int lpos = atomicAdd(&lc[kmin], 1u);
  __syncthreads();
  if (tid < KE) base[tid] = atomicAdd(&cnt[tid], lc[tid]);
  __syncthreads();
  bucket[(size_t)kmin * NB + (int)(base[kmin] + lpos)] = b;
}

// ---- pass 2: recompute winner rows (plain bf16-hi), write f32 out
__global__ __launch_bounds__(256) void ae_pass2(
    const float* __restrict__ x,
    const unsigned short* __restrict__ w1h, const float* __restrict__ b1,
    const unsigned short* __restrict__ w2h, const float* __restrict__ b2,
    const unsigned int* __restrict__ cnt, const int* __restrict__ bucket,
    float* __restrict__ out) {
  __shared__ unsigned short hs[64][NH + 8];                  // 33792 B
  __shared__ union {
    struct { unsigned short xs[64][40]; unsigned short w1s[NH][40]; } a;
    struct { unsigned short w2ts[32][NH + 8]; } b;
  } u;
  __shared__ int rid[64];

  const int k = blockIdx.x & 7;
  const int cv = (int)cnt[k];
  const int t0 = (blockIdx.x >> 3) * 64;
  if (t0 >= cv) return;                     // uniform exit before any barrier
  const int nrows = min(64, cv - t0);

  const int tid = threadIdx.x;
  const int wv = tid >> 6;
  const int lane = tid & 63;
  const int lo = lane & 15;
  const int quad = lane >> 4;
  const int srow = tid >> 2, scol = (tid & 3) * 8;

  if (tid < 64) {
    int idx = t0 + tid;
    rid[tid] = bucket[(size_t)k * NB + (idx < cv ? idx : t0)];
  }
  __syncthreads();
  const int grow = rid[srow];

  f32x4 acc1[4][4];
#pragma unroll
  for (int mt = 0; mt < 4; ++mt)
#pragma unroll
    for (int nt = 0; nt < 4; ++nt) acc1[mt][nt] = (f32x4){0.f, 0.f, 0.f, 0.f};

  for (int kk = 0; kk < ND; kk += 32) {
    float4 xa = *(const float4*)&x[(size_t)grow * ND + kk + scol];
    float4 xb = *(const float4*)&x[(size_t)grow * ND + kk + scol + 4];
    __syncthreads();
    unsigned short t[8];
    t[0] = f2bf(xa.x); t[1] = f2bf(xa.y); t[2] = f2bf(xa.z); t[3] = f2bf(xa.w);
    t[4] = f2bf(xb.x); t[5] = f2bf(xb.y); t[6] = f2bf(xb.z); t[7] = f2bf(xb.w);
    *(u16x8*)&u.a.xs[srow][scol] = *(u16x8*)t;
#pragma unroll
    for (int p = 0; p < 4; ++p) {
      int j = p * 64 + srow;
      *(u16x8*)&u.a.w1s[j][scol] = *(const u16x8*)&w1h[((size_t)k * NH + j) * ND + kk + scol];
    }
    __syncthreads();
    s16x8 af[4], bfr[4];
#pragma unroll
    for (int mt = 0; mt < 4; ++mt) af[mt] = *(const s16x8*)&u.a.xs[mt * 16 + lo][quad * 8];
#pragma unroll
    for (int nt = 0; nt < 4; ++nt)
      bfr[nt] = *(const s16x8*)&u.a.w1s[wv * 64 + nt * 16 + lo][quad * 8];
#pragma unroll
    for (int mt = 0; mt < 4; ++mt)
#pragma unroll
      for (int nt = 0; nt < 4; ++nt)
        acc1[mt][nt] = __builtin_amdgcn_mfma_f32_16x16x32_bf16(af[mt], bfr[nt], acc1[mt][nt], 0, 0, 0);
  }
  __syncthreads();

#pragma unroll
  for (int nt = 0; nt < 4; ++nt) {
    float b1v = b1[(size_t)k * NH + wv * 64 + nt * 16 + lo];
#pragma unroll
    for (int mt = 0; mt < 4; ++mt)
#pragma unroll
      for (int i = 0; i < 4; ++i) {
        float v = acc1[mt][nt][i] + b1v;
        v = v > 0.f ? v : 0.f;
        hs[mt * 16 + quad * 4 + i][wv * 64 + nt * 16 + lo] = f2bf(v);
      }
  }
  __syncthreads();

  for (int c = 0; c < ND / 32; ++c) {
    const int d2b = c * 32;
#pragma unroll
    for (int p = 0; p < 4; ++p) {
      int d2 = p * 8 + (tid >> 5);
      int jc = (tid & 31) * 8;
      *(u16x8*)&u.b.w2ts[d2][jc] = *(const u16x8*)&w2h[((size_t)k * ND + d2b + d2) * NH + jc];
    }
    __syncthreads();

    f32x4 acc2[2];
    acc2[0] = (f32x4){0.f, 0.f, 0.f, 0.f};
    acc2[1] = (f32x4){0.f, 0.f, 0.f, 0.f};
#pragma unroll
    for (int kc = 0; kc < NH; kc += 32) {
      s16x8 af = *(const s16x8*)&hs[wv * 16 + lo][kc + quad * 8];
#pragma unroll
      for (int nt = 0; nt < 2; ++nt) {
        s16x8 bfr = *(const s16x8*)&u.b.w2ts[nt * 16 + lo][kc + quad * 8];
        acc2[nt] = __builtin_amdgcn_mfma_f32_16x16x32_bf16(af, bfr, acc2[nt], 0, 0, 0);
      }
    }
#pragma unroll
    for (int nt = 0; nt < 2; ++nt) {
      float b2v = b2[(size_t)k * ND + d2b + nt * 16 + lo];
#pragma unroll
      for (int i = 0; i < 4; ++i) {
        int row = wv * 16 + quad * 4 + i;
        if (row < nrows)
          out[(size_t)rid[row] * ND + d2b + nt * 16 + lo] = acc2[nt][i] + b2v;
      }
    }
    __syncthreads();
  }
}

extern "C" void kernel_launch(void* const* d_in, const int* in_sizes, int n_in,
                              void* d_out, int out_size, void* d_ws, size_t ws_size,
                              hipStream_t stream) {
  (void)in_sizes; (void)n_in; (void)out_size; (void)ws_size;
  const float* x  = (const float*)d_in[0];
  const float* W1 = (const float*)d_in[1];
  const float* b1 = (const float*)d_in[2];
  const float* W2 = (const float*)d_in[3];
  const float* b2 = (const float*)d_in[4];
  float* out = (float*)d_out;

  char* ws = (char*)d_ws;
  const size_t szW = (size_t)KE * ND * NH * sizeof(unsigned short);  // 4 MB
  const size_t szX = (size_t)NB * ND * sizeof(unsigned short);       // 16.78 MB
  unsigned short* w1h = (unsigned short*)(ws);
  unsigned short* w1l = (unsigned short*)(ws + szW);
  unsigned short* w2h = (unsigned short*)(ws + 2 * szW);
  unsigned short* w2l = (unsigned short*)(ws + 3 * szW);
  unsigned short* xh  = (unsigned short*)(ws + 4 * szW);
  unsigned short* xl  = (unsigned short*)(ws + 4 * szW + szX);
  char* tail          = ws + 4 * szW + 2 * szX;
  float* err          = (float*)tail;
  int* bucket         = (int*)(tail + (size_t)KE * NB * sizeof(float));
  unsigned int* cnt   = (unsigned int*)(tail + (size_t)KE * NB * sizeof(float)
                                        + (size_t)KE * NB * sizeof(int));
  // ws use ~51 MB

  split_w1<<<1024, 256, 0, stream>>>(W1, w1h, w1l);
  split_w2<<<1024, 256, 0, stream>>>(W2, w2h, w2l);
  split_x<<<NB * ND / 4 / 256, 256, 0, stream>>>(x, xh, xl);
  ae_pass1<<<1024, 256, 0, stream>>>(xh, xl, x, w1h, w1l, b1, w2h, w2l, b2, err);
  hipMemsetAsync(cnt, 0, KE * sizeof(unsigned int), stream);
  ae_argmin<<<NB / 256, 256, 0, stream>>>(err, cnt, bucket);
  ae_pass2<<<1024, 256, 0, stream>>>(x, w1h, b1, w2h, b2, cnt, bucket, out);
}

// Round 5
// 620.261 us; speedup vs baseline: 1.2866x; 1.2866x over previous
//
#include <hip/hip_runtime.h>

// f32 I/O. K=8 expert AEs, B=8192, D=1024, H=256.
//   h = relu(x @ W1[k] + b1[k]); recon = h @ W2[k] + b2[k]
//   err[k,b] = mean((recon-x)^2); out[b] = recon[argmin_k err, b]
// Precision (validated R2): pass1 err via split-bf16 hi/lo 3-product GEMMs;
// pass2 winner recon plain bf16-hi.
// R5: R2-R4 all ~600us with MfmaUtil*dur == MFMA floor -> pure exposed latency
// from 16-line scattered fragment gathers. Fix: PRE-PACK W1/W2/x (hi/lo) into
// MFMA-fragment order [frag][lane][8] so every inner-loop load is a dense
// coalesced 1KB burst (lane*16B). Phase A barrier-free, no LDS staging.
// Phase B: disjoint d2-strip per wave (W2 read once/block from L2; h A-frags
// shared via LDS). hs = 64KB XOR-swizzled union (R4-proven), 2 blocks/CU.

#define KE 8
#define NB 8192
#define ND 1024
#define NH 256

typedef float f32x4 __attribute__((ext_vector_type(4)));
typedef short s16x8 __attribute__((ext_vector_type(8)));
typedef unsigned short u16x8 __attribute__((ext_vector_type(8)));
typedef unsigned short u16x4 __attribute__((ext_vector_type(4)));

__device__ __forceinline__ float bf2f(unsigned short h) {
  union { unsigned int u; float f; } v; v.u = ((unsigned int)h) << 16; return v.f;
}
__device__ __forceinline__ unsigned short f2bf(float f) {
  union { unsigned int u; float f; } v; v.f = f;
  unsigned int u = v.u;
  u += 0x7fffu + ((u >> 16) & 1u);   // RTNE
  return (unsigned short)(u >> 16);
}
__device__ __forceinline__ void split2(float x, unsigned short& hi, unsigned short& lo) {
  hi = f2bf(x);
  lo = f2bf(x - bf2f(hi));
}

// ---- pack W1[k][d][h] f32 -> frag-ordered w1ph/w1pl
// frag g=(k*16+ct)*32+ks holds B[k=quad*8+j][n=ct*16+lo] for kd=ks*32..+32.
__global__ __launch_bounds__(256) void pack_w1(const float* __restrict__ in,
                                               unsigned short* __restrict__ oh,
                                               unsigned short* __restrict__ ol) {
  int gid = blockIdx.x * 256 + threadIdx.x;   // 262144
  int L = gid & 63;
  int g = gid >> 6;
  int ks = g & 31;
  int ct = (g >> 5) & 15;
  int k = g >> 9;
  int col = ct * 16 + (L & 15);
  int kd0 = ks * 32 + (L >> 4) * 8;
  unsigned short th[8], tl[8];
#pragma unroll
  for (int j = 0; j < 8; ++j) {
    float v = in[((size_t)k * ND + kd0 + j) * NH + col];
    split2(v, th[j], tl[j]);
  }
  size_t o = ((size_t)g * 64 + L) * 8;
  *(u16x8*)&oh[o] = *(u16x8*)th;
  *(u16x8*)&ol[o] = *(u16x8*)tl;
}

// ---- pack W2[k][h][d] f32 -> frag-ordered w2ph/w2pl
// frag g=(k*64+dt)*8+ks holds B[k=quad*8+j][n=dt*16+lo] for h=ks*32..+32.
__global__ __launch_bounds__(256) void pack_w2(const float* __restrict__ in,
                                               unsigned short* __restrict__ oh,
                                               unsigned short* __restrict__ ol) {
  int gid = blockIdx.x * 256 + threadIdx.x;   // 262144
  int L = gid & 63;
  int g = gid >> 6;
  int ks = g & 7;
  int dt = (g >> 3) & 63;
  int k = g >> 9;
  int d2 = dt * 16 + (L & 15);
  int h0 = ks * 32 + (L >> 4) * 8;
  unsigned short th[8], tl[8];
#pragma unroll
  for (int j = 0; j < 8; ++j) {
    float v = in[((size_t)k * NH + h0 + j) * ND + d2];
    split2(v, th[j], tl[j]);
  }
  size_t o = ((size_t)g * 64 + L) * 8;
  *(u16x8*)&oh[o] = *(u16x8*)th;
  *(u16x8*)&ol[o] = *(u16x8*)tl;
}

// ---- pack x[b][d] f32 -> frag-ordered xph/xpl
// frag g=rt*32+ks holds A[m=rt*16+lo][kd=ks*32+quad*8+j].
__global__ __launch_bounds__(256) void pack_x(const float* __restrict__ in,
                                              unsigned short* __restrict__ oh,
                                              unsigned short* __restrict__ ol) {
  int gid = blockIdx.x * 256 + threadIdx.x;   // 1048576
  int L = gid & 63;
  int g = gid >> 6;
  int ks = g & 31;
  int rt = g >> 5;
  int row = rt * 16 + (L & 15);
  int kd0 = ks * 32 + (L >> 4) * 8;
  float4 a = *(const float4*)&in[(size_t)row * ND + kd0];
  float4 b = *(const float4*)&in[(size_t)row * ND + kd0 + 4];
  unsigned short th[8], tl[8];
  split2(a.x, th[0], tl[0]); split2(a.y, th[1], tl[1]);
  split2(a.z, th[2], tl[2]); split2(a.w, th[3], tl[3]);
  split2(b.x, th[4], tl[4]); split2(b.y, th[5], tl[5]);
  split2(b.z, th[6], tl[6]); split2(b.w, th[7], tl[7]);
  size_t o = ((size_t)g * 64 + L) * 8;
  *(u16x8*)&oh[o] = *(u16x8*)th;
  *(u16x8*)&ol[o] = *(u16x8*)tl;
}

// ---- pass 1: split-precision err[K][B]. BM=64, grid 1024, expert = bx & 7.
__global__ __launch_bounds__(256, 2) void ae_pass1(
    const unsigned short* __restrict__ xph, const unsigned short* __restrict__ xpl,
    const float* __restrict__ x,
    const unsigned short* __restrict__ w1ph, const unsigned short* __restrict__ w1pl,
    const float* __restrict__ b1,
    const unsigned short* __restrict__ w2ph, const unsigned short* __restrict__ w2pl,
    const float* __restrict__ b2, float* __restrict__ err) {
  __shared__ union {
    struct { unsigned short h[64][256]; unsigned short l[64][256]; } hs;  // 65536 B
    float errp[4][64];
  } s;

  const int tid = threadIdx.x;
  const int wv = tid >> 6;
  const int lane = tid & 63;
  const int lo = lane & 15;
  const int quad = lane >> 4;
  const int k = blockIdx.x & 7;
  const int rtile = blockIdx.x >> 3;
  const int r0 = rtile * 64;

  // ---------- phase A: h = relu(x@W1+b1). Barrier-free, all frags packed.
  f32x4 acc1[4][4];
#pragma unroll
  for (int mt = 0; mt < 4; ++mt)
#pragma unroll
    for (int nt = 0; nt < 4; ++nt) acc1[mt][nt] = (f32x4){0.f, 0.f, 0.f, 0.f};

  for (int it = 0; it < 32; ++it) {
    s16x8 ah[4], al[4], bh[4], bl[4];
#pragma unroll
    for (int mt = 0; mt < 4; ++mt) {
      size_t o = (((size_t)(rtile * 4 + mt) * 32) + it) * 512 + lane * 8;
      ah[mt] = *(const s16x8*)&xph[o];
      al[mt] = *(const s16x8*)&xpl[o];
    }
#pragma unroll
    for (int nt = 0; nt < 4; ++nt) {
      size_t o = (((size_t)(k * 16 + wv * 4 + nt) * 32) + it) * 512 + lane * 8;
      bh[nt] = *(const s16x8*)&w1ph[o];
      bl[nt] = *(const s16x8*)&w1pl[o];
    }
#pragma unroll
    for (int nt = 0; nt < 4; ++nt)
#pragma unroll
      for (int mt = 0; mt < 4; ++mt) {
        acc1[mt][nt] = __builtin_amdgcn_mfma_f32_16x16x32_bf16(ah[mt], bh[nt], acc1[mt][nt], 0, 0, 0);
        acc1[mt][nt] = __builtin_amdgcn_mfma_f32_16x16x32_bf16(ah[mt], bl[nt], acc1[mt][nt], 0, 0, 0);
        acc1[mt][nt] = __builtin_amdgcn_mfma_f32_16x16x32_bf16(al[mt], bh[nt], acc1[mt][nt], 0, 0, 0);
      }
  }

  // epilogue A: +b1, relu, split h -> LDS swizzled (C/D: col=lo, row=quad*4+i)
#pragma unroll
  for (int nt = 0; nt < 4; ++nt) {
    float b1v = b1[(size_t)k * NH + wv * 64 + nt * 16 + lo];
#pragma unroll
    for (int mt = 0; mt < 4; ++mt)
#pragma unroll
      for (int i = 0; i < 4; ++i) {
        float v = acc1[mt][nt][i] + b1v;
        v = v > 0.f ? v : 0.f;
        unsigned short vh, vl;
        split2(v, vh, vl);
        int row = mt * 16 + quad * 4 + i, col = wv * 64 + nt * 16 + lo;
        int sc = col ^ ((row & 7) << 3);
        s.hs.h[row][sc] = vh;
        s.hs.l[row][sc] = vl;
      }
  }
  __syncthreads();   // the ONE inter-phase barrier

  // ---------- phase B: recon = h@W2+b2. Wave wv owns d2-strip [wv*256, +256).
  // W2 frags read ONCE per block (disjoint across waves); h A-frags from LDS.
  float eacc[4][4];
#pragma unroll
  for (int mt = 0; mt < 4; ++mt)
#pragma unroll
    for (int i = 0; i < 4; ++i) eacc[mt][i] = 0.f;

  for (int dt = 0; dt < 16; ++dt) {
    f32x4 acc2[4];
#pragma unroll
    for (int mt = 0; mt < 4; ++mt) acc2[mt] = (f32x4){0.f, 0.f, 0.f, 0.f};

#pragma unroll
    for (int ks = 0; ks < 8; ++ks) {
      s16x8 hah[4], hal[4];
#pragma unroll
      for (int mt = 0; mt < 4; ++mt) {
        int row = mt * 16 + lo;
        int off = row * 256 + ((ks * 32 + quad * 8) ^ ((row & 7) << 3));
        hah[mt] = *(const s16x8*)(&s.hs.h[0][0] + off);
        hal[mt] = *(const s16x8*)(&s.hs.l[0][0] + off);
      }
      size_t wo = (((size_t)(k * 64 + wv * 16 + dt) * 8) + ks) * 512 + lane * 8;
      s16x8 bh = *(const s16x8*)&w2ph[wo];
      s16x8 bl = *(const s16x8*)&w2pl[wo];
#pragma unroll
      for (int mt = 0; mt < 4; ++mt) {
        acc2[mt] = __builtin_amdgcn_mfma_f32_16x16x32_bf16(hah[mt], bh, acc2[mt], 0, 0, 0);
        acc2[mt] = __builtin_amdgcn_mfma_f32_16x16x32_bf16(hah[mt], bl, acc2[mt], 0, 0, 0);
        acc2[mt] = __builtin_amdgcn_mfma_f32_16x16x32_bf16(hal[mt], bh, acc2[mt], 0, 0, 0);
      }
    }
    const int d2 = wv * 256 + dt * 16 + lo;
    float b2v = b2[(size_t)k * ND + d2];
#pragma unroll
    for (int mt = 0; mt < 4; ++mt)
#pragma unroll
      for (int i = 0; i < 4; ++i) {
        int row = mt * 16 + quad * 4 + i;
        float rec = acc2[mt][i] + b2v;
        float xv = x[(size_t)(r0 + row) * ND + d2];
        float dd = rec - xv;
        eacc[mt][i] += dd * dd;
      }
  }

  __syncthreads();   // all hs reads done before errp aliases the union
#pragma unroll
  for (int mt = 0; mt < 4; ++mt)
#pragma unroll
    for (int i = 0; i < 4; ++i) {
      float v = eacc[mt][i];
      v += __shfl_xor(v, 1, 16);
      v += __shfl_xor(v, 2, 16);
      v += __shfl_xor(v, 4, 16);
      v += __shfl_xor(v, 8, 16);
      if (lo == 0) s.errp[wv][mt * 16 + quad * 4 + i] = v;
    }
  __syncthreads();
  if (tid < 64)
    err[(size_t)k * NB + r0 + tid] =
        (s.errp[0][tid] + s.errp[1][tid] + s.errp[2][tid] + s.errp[3][tid]) * (1.0f / (float)ND);
}

// ---- argmin + bucket rows per expert
__global__ __launch_bounds__(256) void ae_argmin(const float* __restrict__ err,
                                                 unsigned int* __restrict__ cnt,
                                                 int* __restrict__ bucket) {
  __shared__ unsigned int lc[KE];
  __shared__ unsigned int base[KE];
  int tid = threadIdx.x;
  if (tid < KE) lc[tid] = 0;
  __syncthreads();
  int b = blockIdx.x * 256 + tid;
  float best = err[b];
  int kmin = 0;
#pragma unroll
  for (int j = 1; j < KE; ++j) {
    float e = err[(size_t)j * NB + b];
    if (e < best) { best = e; kmin = j; }   // strict < == first-min (jnp.argmin)
  }
  unsigned int lpos = atomicAdd(&lc[kmin], 1u);
  __syncthreads();
  if (tid < KE) base[tid] = atomicAdd(&cnt[tid], lc[tid]);
  __syncthreads();
  bucket[(size_t)kmin * NB + (int)(base[kmin] + lpos)] = b;
}

// ---- pass 2: recompute winner rows (bf16-hi, packed W frags), write f32 out
__global__ __launch_bounds__(256) void ae_pass2(
    const float* __restrict__ x,
    const unsigned short* __restrict__ w1ph, const float* __restrict__ b1,
    const unsigned short* __restrict__ w2ph, const float* __restrict__ b2,
    const unsigned int* __restrict__ cnt, const int* __restrict__ bucket,
    float* __restrict__ out) {
  __shared__ unsigned short hs[64][NH + 8];   // 33792 B
  __shared__ unsigned short xs[64][40];       // 5120 B
  __shared__ int rid[64];

  const int k = blockIdx.x & 7;
  const int cv = (int)cnt[k];
  const int t0 = (blockIdx.x >> 3) * 64;
  if (t0 >= cv) return;                     // uniform exit before any barrier
  const int nrows = min(64, cv - t0);

  const int tid = threadIdx.x;
  const int wv = tid >> 6;
  const int lane = tid & 63;
  const int lo = lane & 15;
  const int quad = lane >> 4;
  const int srow = tid >> 2, scol = (tid & 3) * 8;

  if (tid < 64) {
    int idx = t0 + tid;
    rid[tid] = bucket[(size_t)k * NB + (idx < cv ? idx : t0)];
  }
  __syncthreads();
  const int grow = rid[srow];

  f32x4 acc1[4][4];
#pragma unroll
  for (int mt = 0; mt < 4; ++mt)
#pragma unroll
    for (int nt = 0; nt < 4; ++nt) acc1[mt][nt] = (f32x4){0.f, 0.f, 0.f, 0.f};

  for (int it = 0; it < 32; ++it) {
    float4 xa = *(const float4*)&x[(size_t)grow * ND + it * 32 + scol];
    float4 xb = *(const float4*)&x[(size_t)grow * ND + it * 32 + scol + 4];
    s16x8 bfr[4];
#pragma unroll
    for (int nt = 0; nt < 4; ++nt)
      bfr[nt] = *(const s16x8*)&w1ph[(((size_t)(k * 16 + wv * 4 + nt) * 32) + it) * 512 + lane * 8];
    __syncthreads();   // prev frag reads done
    unsigned short t[8];
    t[0] = f2bf(xa.x); t[1] = f2bf(xa.y); t[2] = f2bf(xa.z); t[3] = f2bf(xa.w);
    t[4] = f2bf(xb.x); t[5] = f2bf(xb.y); t[6] = f2bf(xb.z); t[7] = f2bf(xb.w);
    *(u16x8*)&xs[srow][scol] = *(u16x8*)t;
    __syncthreads();
    s16x8 af[4];
#pragma unroll
    for (int mt = 0; mt < 4; ++mt) af[mt] = *(const s16x8*)&xs[mt * 16 + lo][quad * 8];
#pragma unroll
    for (int mt = 0; mt < 4; ++mt)
#pragma unroll
      for (int nt = 0; nt < 4; ++nt)
        acc1[mt][nt] = __builtin_amdgcn_mfma_f32_16x16x32_bf16(af[mt], bfr[nt], acc1[mt][nt], 0, 0, 0);
  }
  __syncthreads();

#pragma unroll
  for (int nt = 0; nt < 4; ++nt) {
    float b1v = b1[(size_t)k * NH + wv * 64 + nt * 16 + lo];
#pragma unroll
    for (int mt = 0; mt < 4; ++mt)
#pragma unroll
      for (int i = 0; i < 4; ++i) {
        float v = acc1[mt][nt][i] + b1v;
        v = v > 0.f ? v : 0.f;
        hs[mt * 16 + quad * 4 + i][wv * 64 + nt * 16 + lo] = f2bf(v);
      }
  }
  __syncthreads();

  // phase B: wave wv owns rows [wv*16, +16); d2 chunks of 32; no barriers.
  for (int c = 0; c < 32; ++c) {
    f32x4 acc2[2];
    acc2[0] = (f32x4){0.f, 0.f, 0.f, 0.f};
    acc2[1] = (f32x4){0.f, 0.f, 0.f, 0.f};
#pragma unroll
    for (int ks = 0; ks < 8; ++ks) {
      s16x8 af = *(const s16x8*)&hs[wv * 16 + lo][ks * 32 + quad * 8];
#pragma unroll
      for (int nt = 0; nt < 2; ++nt) {
        s16x8 bfr = *(const s16x8*)&w2ph[(((size_t)(k * 64 + c * 2 + nt) * 8) + ks) * 512 + lane * 8];
        acc2[nt] = __builtin_amdgcn_mfma_f32_16x16x32_bf16(af, bfr, acc2[nt], 0, 0, 0);
      }
    }
#pragma unroll
    for (int nt = 0; nt < 2; ++nt) {
      float b2v = b2[(size_t)k * ND + c * 32 + nt * 16 + lo];
#pragma unroll
      for (int i = 0; i < 4; ++i) {
        int row = wv * 16 + quad * 4 + i;
        if (row < nrows)
          out[(size_t)rid[row] * ND + c * 32 + nt * 16 + lo] = acc2[nt][i] + b2v;
      }
    }
  }
}

extern "C" void kernel_launch(void* const* d_in, const int* in_sizes, int n_in,
                              void* d_out, int out_size, void* d_ws, size_t ws_size,
                              hipStream_t stream) {
  (void)in_sizes; (void)n_in; (void)out_size; (void)ws_size;
  const float* x  = (const float*)d_in[0];
  const float* W1 = (const float*)d_in[1];
  const float* b1 = (const float*)d_in[2];
  const float* W2 = (const float*)d_in[3];
  const float* b2 = (const float*)d_in[4];
  float* out = (float*)d_out;

  char* ws = (char*)d_ws;
  const size_t szW = (size_t)KE * ND * NH * sizeof(unsigned short);  // 4 MB
  const size_t szX = (size_t)NB * ND * sizeof(unsigned short);       // 16.78 MB
  unsigned short* w1ph = (unsigned short*)(ws);
  unsigned short* w1pl = (unsigned short*)(ws + szW);
  unsigned short* w2ph = (unsigned short*)(ws + 2 * szW);
  unsigned short* w2pl = (unsigned short*)(ws + 3 * szW);
  unsigned short* xph  = (unsigned short*)(ws + 4 * szW);
  unsigned short* xpl  = (unsigned short*)(ws + 4 * szW + szX);
  char* tail           = ws + 4 * szW + 2 * szX;
  float* err           = (float*)tail;
  int* bucket          = (int*)(tail + (size_t)KE * NB * sizeof(float));
  unsigned int* cnt    = (unsigned int*)(tail + (size_t)KE * NB * sizeof(float)
                                         + (size_t)KE * NB * sizeof(int));
  // ws use ~50 MB

  pack_w1<<<1024, 256, 0, stream>>>(W1, w1ph, w1pl);
  pack_w2<<<1024, 256, 0, stream>>>(W2, w2ph, w2pl);
  pack_x<<<4096, 256, 0, stream>>>(x, xph, xpl);
  ae_pass1<<<1024, 256, 0, stream>>>(xph, xpl, x, w1ph, w1pl, b1, w2ph, w2pl, b2, err);
  hipMemsetAsync(cnt, 0, KE * sizeof(unsigned int), stream);
  ae_argmin<<<NB / 256, 256, 0, stream>>>(err, cnt, bucket);
  ae_pass2<<<1024, 256, 0, stream>>>(x, w1ph, b1, w2ph, b2, cnt, bucket, out);
}